// Round 11
// baseline (578.911 us; speedup 1.0000x reference)
//
#include <hip/hip_runtime.h>
#include <hip/hip_bf16.h>
#include <math.h>

#define NN 8192
#define HD 128
#define NB 2
#define EPSF 1e-6f

typedef __attribute__((ext_vector_type(8))) __bf16 bf16x8;
typedef __attribute__((ext_vector_type(4))) float f32x4;

// ---------------- Kernel 1: norm = rsqrt(sum|adj_row| + eps) -----------------
__global__ __launch_bounds__(256) void k_degree(const float* __restrict__ adj,
                                                float* __restrict__ norm) {
    const int row  = blockIdx.x * 4 + (threadIdx.x >> 6);
    const int lane = threadIdx.x & 63;
    const float4* p = (const float4*)(adj + (size_t)row * NN);
    float s = 0.f;
#pragma unroll
    for (int i = 0; i < 32; ++i) {
        float4 v = p[(size_t)i * 64 + lane];
        s += fabsf(v.x) + fabsf(v.y) + fabsf(v.z) + fabsf(v.w);
    }
#pragma unroll
    for (int off = 32; off > 0; off >>= 1) s += __shfl_down(s, off);
    if (lane == 0) norm[row] = rsqrtf(s + EPSF);
}

// ------- Kernel 2: snT[b][h][n] = bf16( (x@W)[b][n][h] * norm[b][n] ) --------
__global__ __launch_bounds__(256) void k_support(const float* __restrict__ x,
                                                 const float* __restrict__ W,
                                                 const float* __restrict__ norm,
                                                 __hip_bfloat16* __restrict__ snT) {
    const int b  = blockIdx.x >> 9;
    const int n0 = (blockIdx.x & 511) * 16;
    __shared__ float xs[16][132];
    const int t = threadIdx.x;
    {
        const int r = t >> 4, c0 = (t & 15) * 8;
        const float* src = x + ((size_t)(b * NN + n0 + r)) * HD + c0;
        *(float4*)&xs[r][c0]     = *(const float4*)src;
        *(float4*)&xs[r][c0 + 4] = *(const float4*)(src + 4);
    }
    __syncthreads();
    const int nl = t & 15;
    const int h0 = (t >> 4) * 8;
    float s[8] = {0.f,0.f,0.f,0.f,0.f,0.f,0.f,0.f};
#pragma unroll 4
    for (int k = 0; k < HD; ++k) {
        const float xv = xs[nl][k];
        const float* wr = W + k * HD + h0;
        float4 wa = *(const float4*)wr;
        float4 wb = *(const float4*)(wr + 4);
        s[0] += xv * wa.x; s[1] += xv * wa.y; s[2] += xv * wa.z; s[3] += xv * wa.w;
        s[4] += xv * wb.x; s[5] += xv * wb.y; s[6] += xv * wb.z; s[7] += xv * wb.w;
    }
    const float nv = norm[b * NN + n0 + nl];
#pragma unroll
    for (int hb = 0; hb < 8; ++hb)
        snT[((size_t)b * HD + h0 + hb) * NN + n0 + nl] = __float2bfloat16(s[hb] * nv);
}

__device__ __forceinline__ bf16x8 cvt8(float4 a, float4 b) {
    bf16x8 r;
    r[0] = (__bf16)a.x; r[1] = (__bf16)a.y; r[2] = (__bf16)a.z; r[3] = (__bf16)a.w;
    r[4] = (__bf16)b.x; r[5] = (__bf16)b.y; r[6] = (__bf16)b.z; r[7] = (__bf16)b.w;
    return r;
}

// ---- Kernel 3: out = elu( norm_m * (adj[b] @ snT[b]^T) + bias ) -------------
// k_degree's memory engine + MFMA. NO LDS, NO barriers, NO staging in the
// K-loop: the mfma_16x16x32 A-fragment is lane(fr,g) = 8 contiguous k of row
// fr, loadable directly from global adj as 2 float4 (32 B/lane/step; the 4
// g-lanes consume each 128 B line fully within the step). Block = 32 m-rows x
// 128 h, 8 waves = 2 m-tiles x 4 h-slices: A shared 4x via L1, B (L2-resident
// snT) shared 2x. Per 32-k step/wave: 2 A-loads + 2 B-loads + cvt + 2 MFMA,
// grouped x4 with static names. VGPR ~95 under (512,4) cap=128 -> 2 blocks/CU
// = 16 waves/CU; waves never couple, so TLP rides the HBM queue exactly like
// k_degree (which sustains ~6 TB/s on the same bytes).
__global__ __launch_bounds__(512, 4) void k_gemm11(const float* __restrict__ adj,
                                                   const __hip_bfloat16* __restrict__ snT,
                                                   const float* __restrict__ norm,
                                                   const float* __restrict__ bias,
                                                   float* __restrict__ out) {
    const int b    = blockIdx.y;
    const int swz  = (blockIdx.x & 7) * 32 + (blockIdx.x >> 3);   // XCD-bijective
    const int m0   = swz * 32;
    const int w    = threadIdx.x >> 6;
    const int mw   = w & 1;        // m-tile owner (16 rows)
    const int hw   = w >> 1;       // h-slice owner (32 h)
    const int lane = threadIdx.x & 63;
    const int fr   = lane & 15;
    const int g    = lane >> 4;

    const float* ap = adj + (size_t)b * NN * NN + (size_t)(m0 + mw * 16 + fr) * NN + g * 8;
    const __hip_bfloat16* bp0 = snT + ((size_t)b * HD + hw * 32 + fr) * NN + g * 8;
    const __hip_bfloat16* bp1 = bp0 + (size_t)16 * NN;

    f32x4 acc0 = {0.f,0.f,0.f,0.f}, acc1 = {0.f,0.f,0.f,0.f};

#pragma unroll 1
    for (int kb = 0; kb < NN / 128; ++kb) {
        const float* a = ap + kb * 128;
        const __hip_bfloat16* q0 = bp0 + kb * 128;
        const __hip_bfloat16* q1 = bp1 + kb * 128;

        float4 Aa[4], Ab[4];
        bf16x8 B0[4], B1[4];
#pragma unroll
        for (int s = 0; s < 4; ++s) {
            Aa[s] = *(const float4*)(a + s * 32);
            Ab[s] = *(const float4*)(a + s * 32 + 4);
        }
#pragma unroll
        for (int s = 0; s < 4; ++s) {
            B0[s] = *(const bf16x8*)(q0 + s * 32);
            B1[s] = *(const bf16x8*)(q1 + s * 32);
        }
#pragma unroll
        for (int s = 0; s < 4; ++s) {
            bf16x8 af = cvt8(Aa[s], Ab[s]);
            acc0 = __builtin_amdgcn_mfma_f32_16x16x32_bf16(af, B0[s], acc0, 0, 0, 0);
            acc1 = __builtin_amdgcn_mfma_f32_16x16x32_bf16(af, B1[s], acc1, 0, 0, 0);
        }
    }

    // ---- fused epilogue: *norm_m + bias, elu ----
    const float* normB = norm + b * NN + m0 + mw * 16;
    float* outB = out + ((size_t)b * NN + m0 + mw * 16) * HD;
    const int h0 = hw * 32;
    const float bv0 = bias[h0 + fr];
    const float bv1 = bias[h0 + 16 + fr];
#pragma unroll
    for (int j = 0; j < 4; ++j) {
        const int r = g * 4 + j;
        const float nm = normB[r];
        float v0 = acc0[j] * nm + bv0;
        float v1 = acc1[j] * nm + bv1;
        v0 = v0 > 0.f ? v0 : expm1f(v0);
        v1 = v1 > 0.f ? v1 : expm1f(v1);
        outB[(size_t)r * HD + h0 + fr]      = v0;
        outB[(size_t)r * HD + h0 + 16 + fr] = v1;
    }
}

extern "C" void kernel_launch(void* const* d_in, const int* in_sizes, int n_in,
                              void* d_out, int out_size, void* d_ws, size_t ws_size,
                              hipStream_t stream) {
    (void)in_sizes; (void)n_in; (void)out_size; (void)ws_size;
    const float* x    = (const float*)d_in[0];
    const float* adj  = (const float*)d_in[1];
    const float* W    = (const float*)d_in[2];
    const float* bias = (const float*)d_in[3];
    float* out = (float*)d_out;

    float* norm = (float*)d_ws;                                    // 16384 f32
    __hip_bfloat16* snT = (__hip_bfloat16*)((char*)d_ws + 65536);  // 2x128x8192 bf16 (4 MB)

    k_degree <<<dim3(NB * NN / 4),  dim3(256), 0, stream>>>(adj, norm);
    k_support<<<dim3(NB * NN / 16), dim3(256), 0, stream>>>(x, W, norm, snT);
    k_gemm11 <<<dim3(256, NB),      dim3(512), 0, stream>>>(adj, snT, norm, bias, out);
}

// Round 15
// 246.814 us; speedup vs baseline: 2.3455x; 2.3455x over previous
//
#include <hip/hip_runtime.h>
#include <hip/hip_bf16.h>
#include <math.h>

#define NN 8192
#define HD 128
#define NB 2
#define EPSF 1e-6f
#define BM 32
#define BK 128
#define NSTEP (NN / BK)   // 64

typedef __attribute__((ext_vector_type(8))) __bf16 bf16x8;
typedef __attribute__((ext_vector_type(4))) float f32x4;

// ---------------- Kernel 1: norm = rsqrt(sum|adj_row| + eps) -----------------
__global__ __launch_bounds__(256) void k_degree(const float* __restrict__ adj,
                                                float* __restrict__ norm) {
    const int row  = blockIdx.x * 4 + (threadIdx.x >> 6);
    const int lane = threadIdx.x & 63;
    const float4* p = (const float4*)(adj + (size_t)row * NN);
    float s = 0.f;
#pragma unroll
    for (int i = 0; i < 32; ++i) {
        float4 v = p[(size_t)i * 64 + lane];
        s += fabsf(v.x) + fabsf(v.y) + fabsf(v.z) + fabsf(v.w);
    }
#pragma unroll
    for (int off = 32; off > 0; off >>= 1) s += __shfl_down(s, off);
    if (lane == 0) norm[row] = rsqrtf(s + EPSF);
}

// --- Kernel 2: snT2[b][n/32][h][n&31] = bf16( (x@W)[b][n][h] * norm[b][n] ) --
// K-PANEL-MAJOR layout: for each 32-n panel all 128 h are contiguous, so the
// gemm's B-fragment load (lane fr,g -> h=h0+fr, chunk g*8) covers ONE
// contiguous 1 KB region per wave instruction (perfect coalescing) instead of
// 16 segments scattered 16 KB apart (the R5-R10 hidden defect).
__global__ __launch_bounds__(256) void k_support(const float* __restrict__ x,
                                                 const float* __restrict__ W,
                                                 const float* __restrict__ norm,
                                                 __hip_bfloat16* __restrict__ snT2) {
    const int b  = blockIdx.x >> 9;
    const int n0 = (blockIdx.x & 511) * 16;
    __shared__ float xs[16][132];
    const int t = threadIdx.x;
    {
        const int r = t >> 4, c0 = (t & 15) * 8;
        const float* src = x + ((size_t)(b * NN + n0 + r)) * HD + c0;
        *(float4*)&xs[r][c0]     = *(const float4*)src;
        *(float4*)&xs[r][c0 + 4] = *(const float4*)(src + 4);
    }
    __syncthreads();
    const int nl = t & 15;
    const int h0 = (t >> 4) * 8;
    float s[8] = {0.f,0.f,0.f,0.f,0.f,0.f,0.f,0.f};
#pragma unroll 4
    for (int k = 0; k < HD; ++k) {
        const float xv = xs[nl][k];
        const float* wr = W + k * HD + h0;
        float4 wa = *(const float4*)wr;
        float4 wb = *(const float4*)(wr + 4);
        s[0] += xv * wa.x; s[1] += xv * wa.y; s[2] += xv * wa.z; s[3] += xv * wa.w;
        s[4] += xv * wb.x; s[5] += xv * wb.y; s[6] += xv * wb.z; s[7] += xv * wb.w;
    }
    const int n  = n0 + nl;
    const float nv = norm[b * NN + n];
    __hip_bfloat16* dst = snT2 + (size_t)b * NN * HD
                        + (size_t)(n >> 5) * (HD * 32) + (n & 31);
#pragma unroll
    for (int hb = 0; hb < 8; ++hb)
        dst[(h0 + hb) * 32] = __float2bfloat16(s[hb] * nv);
}

__device__ __forceinline__ bf16x8 cvt8(float4 a, float4 b) {
    bf16x8 r;
    r[0] = (__bf16)a.x; r[1] = (__bf16)a.y; r[2] = (__bf16)a.z; r[3] = (__bf16)a.w;
    r[4] = (__bf16)b.x; r[5] = (__bf16)b.y; r[6] = (__bf16)b.z; r[7] = (__bf16)b.w;
    return r;
}

// async global->LDS, 16 B per lane (dest = wave-uniform base + lane*16)
__device__ __forceinline__ void gload_lds16(const float* g, void* l) {
    __builtin_amdgcn_global_load_lds(
        (const __attribute__((address_space(1))) void*)g,
        (__attribute__((address_space(3))) void*)l, 16, 0, 0);
}

// ---- Kernel 3: out = elu( norm_m * (adj[b] @ support_norm^T) + bias ) -------
// Byte-identical to the harness-proven R8 kernel EXCEPT B addressing, which
// now follows snT2's k-panel-major layout: Bf load = contiguous 1 KB per wave
// (8 fully-consumed cache lines vs 16 half-consumed before). A path, XOR
// swizzle (both-sides involution), gload_lds staging, barrier pacing, and
// epilogue unchanged.
__global__ __launch_bounds__(256, 4) void k_gemm14(const float* __restrict__ adj,
                                                   const __hip_bfloat16* __restrict__ snT2,
                                                   const float* __restrict__ norm,
                                                   const float* __restrict__ bias,
                                                   float* __restrict__ out) {
    const int b    = blockIdx.y;
    const int swz  = (blockIdx.x & 7) * 32 + (blockIdx.x >> 3);   // XCD-bijective
    const int m0   = swz * BM;
    const int w    = threadIdx.x >> 6;     // wave id = h-slice owner (h0 = w*32)
    const int lane = threadIdx.x & 63;
    const int fr   = lane & 15;
    const int g    = lane >> 4;

    const float* adjB = adj + (size_t)b * NN * NN;
    const __hip_bfloat16* snB = snT2 + (size_t)b * NN * HD;

    __shared__ __align__(16) char Abuf[2][BM * BK * 4];   // 2 x 16 KB

    // staging: wave w, call c covers 16B-granules fg = (w*4+c)*64 + lane;
    // row = fg>>5, in-row slot = (fg&31) ^ (row&7)  (both-sides involution)
    const float* sptr[4];
#pragma unroll
    for (int c = 0; c < 4; ++c) {
        const int fg   = (w * 4 + c) * 64 + lane;
        const int row  = fg >> 5;
        const int gsrc = (fg & 31) ^ (row & 7);
        sptr[c] = adjB + (size_t)(m0 + row) * NN + gsrc * 4;
    }

    // B base: panel-major. lane chunk = (h0+ht*16+fr)*32 + g*8 within panel;
    // panel kp advances by HD*32 = 4096 elements.
    const __hip_bfloat16* bp0 = snB + (size_t)(w * 32 + fr) * 32 + g * 8;
    const __hip_bfloat16* bp1 = bp0 + 16 * 32;

    f32x4 acc[2][2] = {};   // [m-tile][h-tile]
    const int xr = fr & 7;

    // ---- prologue: stage step 0 into buf 0 ----
#pragma unroll
    for (int c = 0; c < 4; ++c)
        gload_lds16(sptr[c], &Abuf[0][(w * 4 + c) * 1024]);

#pragma unroll 1
    for (int s = 0; s < NSTEP; ++s) {
        __syncthreads();               // buf[s&1] staged; prev-step reads done
        const char* lb = Abuf[s & 1];

        // B fragments (coalesced 1 KB/wave-instr; compiler inserts its own
        // RAW waits). Issued before staging so their waits don't drain it.
        bf16x8 Bf[2][4];
#pragma unroll
        for (int ks = 0; ks < 4; ++ks) {
            const size_t kp = (size_t)(s * 4 + ks) * (HD * 32);
            Bf[0][ks] = *(const bf16x8*)(bp0 + kp);
            Bf[1][ks] = *(const bf16x8*)(bp1 + kp);
        }

        // stage next adj tile into the other buffer
        if (s + 1 < NSTEP) {
            char* nb = Abuf[(s + 1) & 1];
#pragma unroll
            for (int c = 0; c < 4; ++c)
                gload_lds16(sptr[c] + (s + 1) * BK, &nb[(w * 4 + c) * 1024]);
        }

        // compute from buf[s&1]
#pragma unroll
        for (int mt = 0; mt < 2; ++mt) {
            const char* rbase = lb + (mt * 16 + fr) * 512;
#pragma unroll
            for (int ks = 0; ks < 4; ++ks) {
                float4 fa = *(const float4*)(rbase + ((ks * 8 + ((g * 2 + 0) ^ xr)) << 4));
                float4 fb = *(const float4*)(rbase + ((ks * 8 + ((g * 2 + 1) ^ xr)) << 4));
                bf16x8 af = cvt8(fa, fb);
                acc[mt][0] = __builtin_amdgcn_mfma_f32_16x16x32_bf16(af, Bf[0][ks], acc[mt][0], 0, 0, 0);
                acc[mt][1] = __builtin_amdgcn_mfma_f32_16x16x32_bf16(af, Bf[1][ks], acc[mt][1], 0, 0, 0);
            }
        }
    }

    // ---- fused epilogue: *norm_m + bias, elu ----
    const float* normB = norm + b * NN + m0;
    float* outB = out + ((size_t)b * NN + m0) * HD;
#pragma unroll
    for (int mt = 0; mt < 2; ++mt)
#pragma unroll
        for (int ht = 0; ht < 2; ++ht) {
            const int h  = w * 32 + ht * 16 + fr;
            const float bv = bias[h];
#pragma unroll
            for (int j = 0; j < 4; ++j) {
                const int r = mt * 16 + g * 4 + j;
                float v = acc[mt][ht][j] * normB[r] + bv;
                v = v > 0.f ? v : expm1f(v);
                outB[(size_t)r * HD + h] = v;
            }
        }
}

extern "C" void kernel_launch(void* const* d_in, const int* in_sizes, int n_in,
                              void* d_out, int out_size, void* d_ws, size_t ws_size,
                              hipStream_t stream) {
    (void)in_sizes; (void)n_in; (void)out_size; (void)ws_size;
    const float* x    = (const float*)d_in[0];
    const float* adj  = (const float*)d_in[1];
    const float* W    = (const float*)d_in[2];
    const float* bias = (const float*)d_in[3];
    float* out = (float*)d_out;

    float* norm = (float*)d_ws;                                     // 16384 f32
    __hip_bfloat16* snT2 = (__hip_bfloat16*)((char*)d_ws + 65536);  // 4 MB, panel-major

    k_degree <<<dim3(NB * NN / 4),  dim3(256), 0, stream>>>(adj, norm);
    k_support<<<dim3(NB * NN / 16), dim3(256), 0, stream>>>(x, W, norm, snT2);
    k_gemm14 <<<dim3(NN / BM, NB),  dim3(256), 0, stream>>>(adj, snT2, norm, bias, out);
}

// Round 16
// 245.154 us; speedup vs baseline: 2.3614x; 1.0068x over previous
//
#include <hip/hip_runtime.h>
#include <hip/hip_bf16.h>
#include <math.h>

#define NN 8192
#define HD 128
#define NB 2
#define EPSF 1e-6f
#define BM 32
#define BK 128
#define NSTEP (NN / BK)   // 64

typedef __attribute__((ext_vector_type(8))) __bf16 bf16x8;
typedef __attribute__((ext_vector_type(4))) float f32x4;

// ---------------- Kernel 1: norm = rsqrt(sum|adj_row| + eps) -----------------
__global__ __launch_bounds__(256) void k_degree(const float* __restrict__ adj,
                                                float* __restrict__ norm) {
    const int row  = blockIdx.x * 4 + (threadIdx.x >> 6);
    const int lane = threadIdx.x & 63;
    const float4* p = (const float4*)(adj + (size_t)row * NN);
    float s = 0.f;
#pragma unroll
    for (int i = 0; i < 32; ++i) {
        float4 v = p[(size_t)i * 64 + lane];
        s += fabsf(v.x) + fabsf(v.y) + fabsf(v.z) + fabsf(v.w);
    }
#pragma unroll
    for (int off = 32; off > 0; off >>= 1) s += __shfl_down(s, off);
    if (lane == 0) norm[row] = rsqrtf(s + EPSF);
}

// --- Kernel 2: snT2[b][n/32][h][n&31] = bf16( (x@W)[b][n][h] * norm[b][n] ) --
// K-panel-major layout (R15-verified): the gemm's B-fragment load covers one
// contiguous 1 KB region per wave instruction.
__global__ __launch_bounds__(256) void k_support(const float* __restrict__ x,
                                                 const float* __restrict__ W,
                                                 const float* __restrict__ norm,
                                                 __hip_bfloat16* __restrict__ snT2) {
    const int b  = blockIdx.x >> 9;
    const int n0 = (blockIdx.x & 511) * 16;
    __shared__ float xs[16][132];
    const int t = threadIdx.x;
    {
        const int r = t >> 4, c0 = (t & 15) * 8;
        const float* src = x + ((size_t)(b * NN + n0 + r)) * HD + c0;
        *(float4*)&xs[r][c0]     = *(const float4*)src;
        *(float4*)&xs[r][c0 + 4] = *(const float4*)(src + 4);
    }
    __syncthreads();
    const int nl = t & 15;
    const int h0 = (t >> 4) * 8;
    float s[8] = {0.f,0.f,0.f,0.f,0.f,0.f,0.f,0.f};
#pragma unroll 4
    for (int k = 0; k < HD; ++k) {
        const float xv = xs[nl][k];
        const float* wr = W + k * HD + h0;
        float4 wa = *(const float4*)wr;
        float4 wb = *(const float4*)(wr + 4);
        s[0] += xv * wa.x; s[1] += xv * wa.y; s[2] += xv * wa.z; s[3] += xv * wa.w;
        s[4] += xv * wb.x; s[5] += xv * wb.y; s[6] += xv * wb.z; s[7] += xv * wb.w;
    }
    const int n  = n0 + nl;
    const float nv = norm[b * NN + n];
    __hip_bfloat16* dst = snT2 + (size_t)b * NN * HD
                        + (size_t)(n >> 5) * (HD * 32) + (n & 31);
#pragma unroll
    for (int hb = 0; hb < 8; ++hb)
        dst[(h0 + hb) * 32] = __float2bfloat16(s[hb] * nv);
}

__device__ __forceinline__ bf16x8 cvt8(float4 a, float4 b) {
    bf16x8 r;
    r[0] = (__bf16)a.x; r[1] = (__bf16)a.y; r[2] = (__bf16)a.z; r[3] = (__bf16)a.w;
    r[4] = (__bf16)b.x; r[5] = (__bf16)b.y; r[6] = (__bf16)b.z; r[7] = (__bf16)b.w;
    return r;
}

// async global->LDS, 16 B per lane (dest = wave-uniform base + lane*16)
__device__ __forceinline__ void gload_lds16(const float* g, void* l) {
    __builtin_amdgcn_global_load_lds(
        (const __attribute__((address_space(1))) void*)g,
        (__attribute__((address_space(3))) void*)l, 16, 0, 0);
}

// ---- Kernel 3: out = elu( norm_m * (adj[b] @ support_norm^T) + bias ) -------
// Composition of two harness-verified pieces (both absmax 0.015625):
//  * R9's counted-vmcnt pipeline: raw s_barrier + s_waitcnt vmcnt(16),
//    stage-ahead-2 into 4 LDS buffers, B one step ahead in ping-pong banks.
//    No vmcnt(0) drain in the main loop.
//  * R15's panel-major coalesced B addressing (1 KB/wave per B instruction).
// Rationale: R9 gained nothing because divergent B saturated the VMEM
// front-end (16 L2 requests per B instr) -- pipeline depth was moot. With B
// coalesced, the barrier-drain stall re-emerges as the limiter, which the
// counted vmcnt removes. Per half-iter: B(k+1)[8] + stage(k+2)[4] issued; at
// WAITN the queue holds st(k+1)4 + B(k+1)8 + st(k+2)4 = 16 -> WAITN(16)
// retires st(k). 4 buffers = 2-barrier overwrite distance.
__global__ __launch_bounds__(256, 2) void k_gemm16(const float* __restrict__ adj,
                                                   const __hip_bfloat16* __restrict__ snT2,
                                                   const float* __restrict__ norm,
                                                   const float* __restrict__ bias,
                                                   float* __restrict__ out) {
    const int b    = blockIdx.y;
    const int swz  = (blockIdx.x & 7) * 32 + (blockIdx.x >> 3);   // XCD-bijective
    const int m0   = swz * BM;
    const int w    = threadIdx.x >> 6;
    const int lane = threadIdx.x & 63;
    const int fr   = lane & 15;
    const int g    = lane >> 4;

    const float* adjB = adj + (size_t)b * NN * NN;
    const __hip_bfloat16* snB = snT2 + (size_t)b * NN * HD;

    __shared__ __align__(16) char Abuf[4][BM * BK * 4];   // 4 x 16 KB

    // staging: wave w, call c covers 16B-granules fg = (w*4+c)*64 + lane;
    // row = fg>>5, in-row slot = (fg&31) ^ (row&7)  (both-sides involution)
    const float* sptr[4];
#pragma unroll
    for (int c = 0; c < 4; ++c) {
        const int fg   = (w * 4 + c) * 64 + lane;
        const int row  = fg >> 5;
        const int gsrc = (fg & 31) ^ (row & 7);
        sptr[c] = adjB + (size_t)(m0 + row) * NN + gsrc * 4;
    }

    // B base: panel-major. lane chunk = (h0+ht*16+fr)*32 + g*8 within panel;
    // panel ks advances by HD*32 = 4096 elements.
    const __hip_bfloat16* bp0 = snB + (size_t)(w * 32 + fr) * 32 + g * 8;
    const __hip_bfloat16* bp1 = bp0 + 16 * 32;

    f32x4 acc[2][2] = {};
    const int xr = fr & 7;
    bf16x8 BfA[2][4], BfB[2][4];   // ping-pong B banks

#define STAGE(idx) do {                                                       \
        char* nb_ = Abuf[(idx) & 3];                                          \
        _Pragma("unroll")                                                     \
        for (int c = 0; c < 4; ++c)                                           \
            gload_lds16(sptr[c] + (idx) * BK, &nb_[(w * 4 + c) * 1024]);      \
    } while (0)
#define LOADB(BX, idx) do {                                                   \
        _Pragma("unroll")                                                     \
        for (int ks = 0; ks < 4; ++ks) {                                      \
            const size_t kp_ = (size_t)((idx) * 4 + ks) * (HD * 32);          \
            BX[0][ks] = *(const bf16x8*)(bp0 + kp_);                          \
            BX[1][ks] = *(const bf16x8*)(bp1 + kp_);                          \
        }                                                                     \
    } while (0)
#define WAITN(n) asm volatile("s_waitcnt vmcnt(" #n ")" ::: "memory")
#define BAR() do { __builtin_amdgcn_s_barrier();                              \
                   __builtin_amdgcn_sched_barrier(0); } while (0)
#define COMPUTE(kidx, BX) do {                                                \
        const char* lb_ = Abuf[(kidx) & 3];                                   \
        _Pragma("unroll")                                                     \
        for (int mt = 0; mt < 2; ++mt) {                                      \
            const char* rbase_ = lb_ + (mt * 16 + fr) * 512;                  \
            _Pragma("unroll")                                                 \
            for (int ks = 0; ks < 4; ++ks) {                                  \
                float4 fa_ = *(const float4*)(rbase_ + ((ks * 8 + ((g * 2 + 0) ^ xr)) << 4)); \
                float4 fb_ = *(const float4*)(rbase_ + ((ks * 8 + ((g * 2 + 1) ^ xr)) << 4)); \
                bf16x8 af_ = cvt8(fa_, fb_);                                  \
                acc[mt][0] = __builtin_amdgcn_mfma_f32_16x16x32_bf16(af_, BX[0][ks], acc[mt][0], 0, 0, 0); \
                acc[mt][1] = __builtin_amdgcn_mfma_f32_16x16x32_bf16(af_, BX[1][ks], acc[mt][1], 0, 0, 0); \
            }                                                                 \
        }                                                                     \
    } while (0)

    // ---- prologue: stage 0,1; B(0) into bank A ----
    STAGE(0);
    STAGE(1);
    LOADB(BfA, 0);

    // ---- main loop: halves k (even) and k+1; stages k+2, k+3 ----
#pragma unroll 1
    for (int k = 0; k < NSTEP - 3; k += 2) {
        LOADB(BfB, k + 1);
        STAGE(k + 2);
        WAITN(16); BAR();
        COMPUTE(k, BfA);

        LOADB(BfA, k + 2);
        STAGE(k + 3);
        WAITN(16); BAR();
        COMPUTE(k + 1, BfB);
    }

    // ---- tail: k = NSTEP-2, NSTEP-1 ----
    LOADB(BfB, NSTEP - 1);
    WAITN(0); BAR();
    COMPUTE(NSTEP - 2, BfA);

    WAITN(0); BAR();
    COMPUTE(NSTEP - 1, BfB);

#undef STAGE
#undef LOADB
#undef WAITN
#undef BAR
#undef COMPUTE

    // ---- fused epilogue: *norm_m + bias, elu ----
    const float* normB = norm + b * NN + m0;
    float* outB = out + ((size_t)b * NN + m0) * HD;
#pragma unroll
    for (int mt = 0; mt < 2; ++mt)
#pragma unroll
        for (int ht = 0; ht < 2; ++ht) {
            const int h  = w * 32 + ht * 16 + fr;
            const float bv = bias[h];
#pragma unroll
            for (int j = 0; j < 4; ++j) {
                const int r = mt * 16 + g * 4 + j;
                float v = acc[mt][ht][j] * normB[r] + bv;
                v = v > 0.f ? v : expm1f(v);
                outB[(size_t)r * HD + h] = v;
            }
        }
}

extern "C" void kernel_launch(void* const* d_in, const int* in_sizes, int n_in,
                              void* d_out, int out_size, void* d_ws, size_t ws_size,
                              hipStream_t stream) {
    (void)in_sizes; (void)n_in; (void)out_size; (void)ws_size;
    const float* x    = (const float*)d_in[0];
    const float* adj  = (const float*)d_in[1];
    const float* W    = (const float*)d_in[2];
    const float* bias = (const float*)d_in[3];
    float* out = (float*)d_out;

    float* norm = (float*)d_ws;                                     // 16384 f32
    __hip_bfloat16* snT2 = (__hip_bfloat16*)((char*)d_ws + 65536);  // 4 MB, panel-major

    k_degree <<<dim3(NB * NN / 4),  dim3(256), 0, stream>>>(adj, norm);
    k_support<<<dim3(NB * NN / 16), dim3(256), 0, stream>>>(x, W, norm, snT2);
    k_gemm16 <<<dim3(NN / BM, NB),  dim3(256), 0, stream>>>(adj, snT2, norm, bias, out);
}

// Round 17
// 236.151 us; speedup vs baseline: 2.4514x; 1.0381x over previous
//
#include <hip/hip_runtime.h>
#include <hip/hip_bf16.h>
#include <math.h>

#define NN 8192
#define HD 128
#define NB 2
#define EPSF 1e-6f
#define BM 64
#define BK 128
#define NSTEP (NN / BK)   // 64

typedef __attribute__((ext_vector_type(8))) __bf16 bf16x8;
typedef __attribute__((ext_vector_type(4))) float f32x4;

// ---------------- Kernel 1: norm = rsqrt(sum|adj_row| + eps) -----------------
__global__ __launch_bounds__(256) void k_degree(const float* __restrict__ adj,
                                                float* __restrict__ norm) {
    const int row  = blockIdx.x * 4 + (threadIdx.x >> 6);
    const int lane = threadIdx.x & 63;
    const float4* p = (const float4*)(adj + (size_t)row * NN);
    float s = 0.f;
#pragma unroll
    for (int i = 0; i < 32; ++i) {
        float4 v = p[(size_t)i * 64 + lane];
        s += fabsf(v.x) + fabsf(v.y) + fabsf(v.z) + fabsf(v.w);
    }
#pragma unroll
    for (int off = 32; off > 0; off >>= 1) s += __shfl_down(s, off);
    if (lane == 0) norm[row] = rsqrtf(s + EPSF);
}

// --- Kernel 2: snT2[b][n/32][h][n&31] = bf16( (x@W)[b][n][h] * norm[b][n] ) --
// K-panel-major layout (R15-verified): gemm B loads are 1 KB/wave contiguous.
__global__ __launch_bounds__(256) void k_support(const float* __restrict__ x,
                                                 const float* __restrict__ W,
                                                 const float* __restrict__ norm,
                                                 __hip_bfloat16* __restrict__ snT2) {
    const int b  = blockIdx.x >> 9;
    const int n0 = (blockIdx.x & 511) * 16;
    __shared__ float xs[16][132];
    const int t = threadIdx.x;
    {
        const int r = t >> 4, c0 = (t & 15) * 8;
        const float* src = x + ((size_t)(b * NN + n0 + r)) * HD + c0;
        *(float4*)&xs[r][c0]     = *(const float4*)src;
        *(float4*)&xs[r][c0 + 4] = *(const float4*)(src + 4);
    }
    __syncthreads();
    const int nl = t & 15;
    const int h0 = (t >> 4) * 8;
    float s[8] = {0.f,0.f,0.f,0.f,0.f,0.f,0.f,0.f};
#pragma unroll 4
    for (int k = 0; k < HD; ++k) {
        const float xv = xs[nl][k];
        const float* wr = W + k * HD + h0;
        float4 wa = *(const float4*)wr;
        float4 wb = *(const float4*)(wr + 4);
        s[0] += xv * wa.x; s[1] += xv * wa.y; s[2] += xv * wa.z; s[3] += xv * wa.w;
        s[4] += xv * wb.x; s[5] += xv * wb.y; s[6] += xv * wb.z; s[7] += xv * wb.w;
    }
    const int n  = n0 + nl;
    const float nv = norm[b * NN + n];
    __hip_bfloat16* dst = snT2 + (size_t)b * NN * HD
                        + (size_t)(n >> 5) * (HD * 32) + (n & 31);
#pragma unroll
    for (int hb = 0; hb < 8; ++hb)
        dst[(h0 + hb) * 32] = __float2bfloat16(s[hb] * nv);
}

__device__ __forceinline__ bf16x8 cvt8(float4 a, float4 b) {
    bf16x8 r;
    r[0] = (__bf16)a.x; r[1] = (__bf16)a.y; r[2] = (__bf16)a.z; r[3] = (__bf16)a.w;
    r[4] = (__bf16)b.x; r[5] = (__bf16)b.y; r[6] = (__bf16)b.z; r[7] = (__bf16)b.w;
    return r;
}

// async global->LDS, 16 B per lane (dest = wave-uniform base + lane*16)
__device__ __forceinline__ void gload_lds16(const float* g, void* l) {
    __builtin_amdgcn_global_load_lds(
        (const __attribute__((address_space(1))) void*)g,
        (__attribute__((address_space(3))) void*)l, 16, 0, 0);
}

// ---- Kernel 3: out = elu( norm_m * (adj[b] @ support_norm^T) + bias ) -------
// R16 structure with BM=64: B (snT2) traffic halves to 537 MB total -- the
// L2/L3 B-path was the residual limiter (1.07 GB at ~10 TB/s ~= 107 us; fits
// R7's regression quantitatively). 512 threads = 8 waves = 2 m-halves x 4
// h-slices; LDS = 4 x 32 KB (1 block/CU, tolerated because the counted-vmcnt
// pipeline has no in-loop drain). Per half-iter: B(k+1)[8] + stage(k+2)[4
// calls/thread] -> WAITN(16) retires st(k) exactly as R16. Both-sides XOR
// swizzle and panel-major B unchanged (verified absmax 0.015625 for 12 rounds).
__global__ __launch_bounds__(512, 2) void k_gemm17(const float* __restrict__ adj,
                                                   const __hip_bfloat16* __restrict__ snT2,
                                                   const float* __restrict__ norm,
                                                   const float* __restrict__ bias,
                                                   float* __restrict__ out) {
    const int b    = blockIdx.y;
    const int swz  = (blockIdx.x & 7) * 16 + (blockIdx.x >> 3);   // XCD-bijective (128 = 8x16)
    const int m0   = swz * BM;
    const int w    = threadIdx.x >> 6;     // 0..7
    const int mh   = w & 1;                // m-half owner (32 rows)
    const int hs   = w >> 1;               // h-slice owner (32 h)
    const int lane = threadIdx.x & 63;
    const int fr   = lane & 15;
    const int g    = lane >> 4;
    const int xr   = fr & 7;

    const float* adjB = adj + (size_t)b * NN * NN;
    const __hip_bfloat16* snB = snT2 + (size_t)b * NN * HD;

    __shared__ __align__(16) char Abuf[4][BM * BK * 4];   // 4 x 32 KB

    // staging: thread call c covers 16B-granule fg = c*512 + w*64 + lane
    // (2048 granules = 64 rows x 32); row = fg>>5, slot = (fg&31)^(row&7).
    const float* sptr[4];
#pragma unroll
    for (int c = 0; c < 4; ++c) {
        const int fg   = c * 512 + w * 64 + lane;
        const int row  = fg >> 5;
        const int gsrc = (fg & 31) ^ (row & 7);
        sptr[c] = adjB + (size_t)(m0 + row) * NN + gsrc * 4;
    }

    // B base: panel-major; lane chunk = (hs*32 + ht*16 + fr)*32 + g*8
    const __hip_bfloat16* bp0 = snB + (size_t)(hs * 32 + fr) * 32 + g * 8;
    const __hip_bfloat16* bp1 = bp0 + 16 * 32;

    f32x4 acc[2][2] = {};   // [m-tile within half][h-tile]
    bf16x8 BfA[2][4], BfB[2][4];

#define STAGE(idx) do {                                                       \
        char* nb_ = Abuf[(idx) & 3];                                          \
        _Pragma("unroll")                                                     \
        for (int c = 0; c < 4; ++c)                                           \
            gload_lds16(sptr[c] + (idx) * BK, &nb_[c * 8192 + w * 1024]);     \
    } while (0)
#define LOADB(BX, idx) do {                                                   \
        _Pragma("unroll")                                                     \
        for (int ks = 0; ks < 4; ++ks) {                                      \
            const size_t kp_ = (size_t)((idx) * 4 + ks) * (HD * 32);          \
            BX[0][ks] = *(const bf16x8*)(bp0 + kp_);                          \
            BX[1][ks] = *(const bf16x8*)(bp1 + kp_);                          \
        }                                                                     \
    } while (0)
#define WAITN(n) asm volatile("s_waitcnt vmcnt(" #n ")" ::: "memory")
#define BAR() do { __builtin_amdgcn_s_barrier();                              \
                   __builtin_amdgcn_sched_barrier(0); } while (0)
#define COMPUTE(kidx, BX) do {                                                \
        const char* lb_ = Abuf[(kidx) & 3];                                   \
        _Pragma("unroll")                                                     \
        for (int mt = 0; mt < 2; ++mt) {                                      \
            const char* rbase_ = lb_ + (mh * 32 + mt * 16 + fr) * 512;        \
            _Pragma("unroll")                                                 \
            for (int ks = 0; ks < 4; ++ks) {                                  \
                float4 fa_ = *(const float4*)(rbase_ + ((ks * 8 + ((g * 2 + 0) ^ xr)) << 4)); \
                float4 fb_ = *(const float4*)(rbase_ + ((ks * 8 + ((g * 2 + 1) ^ xr)) << 4)); \
                bf16x8 af_ = cvt8(fa_, fb_);                                  \
                acc[mt][0] = __builtin_amdgcn_mfma_f32_16x16x32_bf16(af_, BX[0][ks], acc[mt][0], 0, 0, 0); \
                acc[mt][1] = __builtin_amdgcn_mfma_f32_16x16x32_bf16(af_, BX[1][ks], acc[mt][1], 0, 0, 0); \
            }                                                                 \
        }                                                                     \
    } while (0)

    // ---- prologue: stage 0,1; B(0) into bank A ----
    STAGE(0);
    STAGE(1);
    LOADB(BfA, 0);

    // ---- main loop ----
#pragma unroll 1
    for (int k = 0; k < NSTEP - 3; k += 2) {
        LOADB(BfB, k + 1);
        STAGE(k + 2);
        WAITN(16); BAR();
        COMPUTE(k, BfA);

        LOADB(BfA, k + 2);
        STAGE(k + 3);
        WAITN(16); BAR();
        COMPUTE(k + 1, BfB);
    }

    // ---- tail ----
    LOADB(BfB, NSTEP - 1);
    WAITN(0); BAR();
    COMPUTE(NSTEP - 2, BfA);

    WAITN(0); BAR();
    COMPUTE(NSTEP - 1, BfB);

#undef STAGE
#undef LOADB
#undef WAITN
#undef BAR
#undef COMPUTE

    // ---- fused epilogue: *norm_m + bias, elu ----
    const float* normB = norm + b * NN + m0;
    float* outB = out + ((size_t)b * NN + m0) * HD;
#pragma unroll
    for (int mt = 0; mt < 2; ++mt)
#pragma unroll
        for (int ht = 0; ht < 2; ++ht) {
            const int h  = hs * 32 + ht * 16 + fr;
            const float bv = bias[h];
#pragma unroll
            for (int j = 0; j < 4; ++j) {
                const int r = mh * 32 + mt * 16 + g * 4 + j;
                float v = acc[mt][ht][j] * normB[r] + bv;
                v = v > 0.f ? v : expm1f(v);
                outB[(size_t)r * HD + h] = v;
            }
        }
}

extern "C" void kernel_launch(void* const* d_in, const int* in_sizes, int n_in,
                              void* d_out, int out_size, void* d_ws, size_t ws_size,
                              hipStream_t stream) {
    (void)in_sizes; (void)n_in; (void)out_size; (void)ws_size;
    const float* x    = (const float*)d_in[0];
    const float* adj  = (const float*)d_in[1];
    const float* W    = (const float*)d_in[2];
    const float* bias = (const float*)d_in[3];
    float* out = (float*)d_out;

    float* norm = (float*)d_ws;                                     // 16384 f32
    __hip_bfloat16* snT2 = (__hip_bfloat16*)((char*)d_ws + 65536);  // 4 MB, panel-major

    k_degree <<<dim3(NB * NN / 4),  dim3(256), 0, stream>>>(adj, norm);
    k_support<<<dim3(NB * NN / 16), dim3(256), 0, stream>>>(x, W, norm, snT2);
    k_gemm17 <<<dim3(NN / BM, NB),  dim3(512), 0, stream>>>(adj, snT2, norm, bias, out);
}